// Round 11
// baseline (63.850 us; speedup 1.0000x reference)
//
#include <hip/hip_runtime.h>

// RPNPooling: B=2, H=128, W=128, C=256, N=512, POOL=14
// out[q,i,j,ch], q in [0,1024), i,j in [0,14), ch in [0,256)
// Reference quirk: r-axis (feature H index) derives from roi x-coords,
// c-axis (feature W index) derives from roi y-coords. Replicated verbatim.
//
// R10 = R9 (register-rolling wave-per-(q,i), sc0 sc1 nt streaming stores)
//     + fast deterministic ROI clustering (counting sort by 128 spatial
//       buckets, ~2 us) so each XCD's 128 ROIs form one ~4 MB feature
//       region that stays L2-resident behind the L2-bypassing writes.
// Discriminates: L3-write-thrash model (predict -6..-9 us) vs
// mixed-stream-limit model (predict neutral -> roofline).

typedef float f32x4 __attribute__((ext_vector_type(4)));

#define NROI 1024
#define WAVES_TOTAL (NROI * 14)      // 14336
#define THREADS 256                  // 4 waves/block
#define NBLK (WAVES_TOTAL / 4)       // 3584, % 8 == 0
#define NBUCKET 128

__device__ __forceinline__ unsigned spread3(unsigned v) {
    v &= 7u;
    return (v & 1u) | ((v & 2u) << 1) | ((v & 4u) << 2);
}

// One block, 1024 threads: stable counting sort of ROI ids by
// (batch, Morton(x1>>4, y1>>4)) -> 128 buckets. Deterministic.
__global__ __launch_bounds__(1024) void roi_bucket_kernel(
    const int* __restrict__ roi, int* __restrict__ perm)
{
    __shared__ short bkt[NROI];
    __shared__ int cnt[NBUCKET];
    __shared__ int basearr[NBUCKET];
    const int t = threadIdx.x;
    if (t < NBUCKET) cnt[t] = 0;
    __syncthreads();

    const int4 rr = ((const int4*)roi)[t];
    const int b = t >> 9;
    // r-axis start = x1 = rr.y; c-axis start = y1 = rr.x (reference swap)
    const unsigned m = spread3((unsigned)rr.y >> 4) | (spread3((unsigned)rr.x >> 4) << 1);
    const int bucket = (b << 6) | (int)m;
    bkt[t] = (short)bucket;
    atomicAdd(&cnt[bucket], 1);
    __syncthreads();

    if (t == 0) {
        int acc = 0;
        for (int k = 0; k < NBUCKET; ++k) { basearr[k] = acc; acc += cnt[k]; }
    }
    __syncthreads();

    // Stable rank: count earlier q with same bucket (LDS broadcast scan).
    int rank = 0;
    for (int k = 0; k < t; ++k) rank += (bkt[k] == (short)bucket);
    perm[basearr[bucket] + rank] = t;
}

__global__ __launch_bounds__(THREADS) void rpn_pool_kernel(
    const float* __restrict__ feat,   // [2,128,128,256]
    const int*   __restrict__ roi,    // [1024,4] = y1,x1,y2,x2
    const int*   __restrict__ perm,   // [1024] clustered schedule
    float*       __restrict__ out)    // [1024,14,14,256]
{
    const int lane = threadIdx.x & 63;
    const int wv   = threadIdx.x >> 6;

    // XCD chunking (bijective): XCD k owns schedule slots [k*128,(k+1)*128)
    // = one spatially-clustered ~4 MB feature region.
    const int d   = blockIdx.x;
    const int blk = (d & 7) * (NBLK / 8) + (d >> 3);
    const int W   = blk * 4 + wv;     // wave id in [0, 14336)
    const int g   = W / 14;           // schedule slot
    const int i   = W - g * 14;       // this wave's output row
    const int q   = perm[g];          // actual ROI index
    const int b   = q >> 9;

    const int4 rr = ((const int4*)roi)[q];
    const int y1 = rr.x, x1 = rr.y, y2 = rr.z, x2 = rr.w;
    const int sR = x2 - x1;           // H-extent from x coords (reference swap)
    const int sC = y2 - y1;           // W-extent from y coords

    // Row constants for this wave (fixed rows r0, r1)
    const int pr  = i * sR;
    const int ir0 = pr / 14;
    const float fr  = (float)(pr - ir0 * 14) * (1.0f / 14.0f);
    const float wr1 = 1.0f - fr;
    const int r0 = ir0;
    const int r1 = min(ir0 + 1, sR - 1);

    const size_t SB4 = (size_t)128 * 128 * 64;   // f32x4 strides
    const size_t SR4 = (size_t)128 * 64;
    const f32x4* base = (const f32x4*)feat + (size_t)b * SB4
                        + (size_t)x1 * SR4 + (size_t)y1 * 64 + lane;
    const f32x4* rowA = base + (size_t)r0 * SR4;   // row r0, column-indexed
    const f32x4* rowB = base + (size_t)r1 * SR4;

    // Prologue: columns 0 and cB=min(1,sC-1)=1 (sC >= 8)
    int cA = 0, cB = min(1, sC - 1);
    f32x4 a0 = rowA[0];
    f32x4 a1 = rowA[(size_t)cB * 64];
    f32x4 b0 = rowB[0];
    f32x4 b1 = rowB[(size_t)cB * 64];

    f32x4* outp = (f32x4*)out + ((size_t)q * 196 + (size_t)i * 14) * 64 + lane;

    for (int j = 0; j < 14; ++j) {
        const int pc = j * sC;                    // cA == pc/14 (invariant)
        const float fc = (float)(pc - cA * 14) * (1.0f / 14.0f);

        // Prefetch next step's new column (wave-uniform branch).
        int nA = cA, nB = cB;
        f32x4 p0, p1;
        bool adv = false;
        if (j < 13) {
            nA = ((j + 1) * sC) / 14;
            nB = min(nA + 1, sC - 1);
            if (nB > cB) {
                p0 = rowA[(size_t)nB * 64];
                p1 = rowB[(size_t)nB * 64];
                adv = true;
            }
        }

        f32x4 o = (a0 * (1.0f - fc) + a1 * fc) * wr1 + (b0 * (1.0f - fc) + b1 * fc) * fr;

        // Streaming store: bypass L2 allocation, non-temporal at L3.
        f32x4* p = outp + (size_t)j * 64;
        asm volatile("global_store_dwordx4 %0, %1, off sc0 sc1 nt"
                     :: "v"(p), "v"(o) : "memory");

        if (nA > cA) { a0 = a1; b0 = b1; }        // adv => nA > cA; coherent
        if (adv)     { a1 = p0; b1 = p1; }
        cA = nA; cB = nB;
    }
}

extern "C" void kernel_launch(void* const* d_in, const int* in_sizes, int n_in,
                              void* d_out, int out_size, void* d_ws, size_t ws_size,
                              hipStream_t stream) {
    const float* feat = (const float*)d_in[0];
    const int*   roi  = (const int*)d_in[1];
    float* out = (float*)d_out;
    int*   perm = (int*)d_ws;

    roi_bucket_kernel<<<1, 1024, 0, stream>>>(roi, perm);
    rpn_pool_kernel<<<NBLK, THREADS, 0, stream>>>(feat, roi, perm, out);
}

// Round 12
// 50.350 us; speedup vs baseline: 1.2681x; 1.2681x over previous
//
#include <hip/hip_runtime.h>

// RPNPooling: B=2, H=128, W=128, C=256, N=512, POOL=14
// out[q,i,j,ch], q in [0,1024), i,j in [0,14), ch in [0,256)
// Reference quirk: r-axis (feature H index) derives from roi x-coords,
// c-axis (feature W index) derives from roi y-coords. Replicated verbatim.
//
// FINAL (R9 structure, best measured: 50.3-50.4 us across two runs).
// Wave-per-(q,i) output row; register-rolling bilinear taps (columns advance
// monotonically by <=1 per j-step, slope sC/14 <= 15/14), one-step-ahead
// prefetch, no LDS, no barriers; contiguous 14 KB store run per wave via
// streaming stores (sc0 sc1 nt — best of {plain 54.1, nt 50.9, sc0sc1nt 50.3}).
// XCD-chunked blockIdx.
//
// Established by single-variable A/B across R3-R10: read volume (-2.6us),
// read placement (0), LDS vs registers (0), write contiguity (0), spatial
// clustering (0, tested twice unconfounded in the main kernel). Remaining
// time = compulsory 205.5 MB write + 33.5 MB read mixed-stream at ~4.7 TB/s
// effective — the machine's mixed R/W rate for this access pattern.

typedef float f32x4 __attribute__((ext_vector_type(4)));

#define NROI 1024
#define WAVES_TOTAL (NROI * 14)      // 14336
#define THREADS 256                  // 4 waves/block
#define NBLK (WAVES_TOTAL / 4)       // 3584, % 8 == 0

__global__ __launch_bounds__(THREADS) void rpn_pool_kernel(
    const float* __restrict__ feat,   // [2,128,128,256]
    const int*   __restrict__ roi,    // [1024,4] = y1,x1,y2,x2
    float*       __restrict__ out)    // [1024,14,14,256]
{
    const int lane = threadIdx.x & 63;
    const int wv   = threadIdx.x >> 6;

    // XCD chunking (bijective, 3584 % 8 == 0): XCD k owns q in [k*128,(k+1)*128)
    // -> one contiguous ~25 MB output slab per XCD.
    const int d   = blockIdx.x;
    const int blk = (d & 7) * (NBLK / 8) + (d >> 3);
    const int W   = blk * 4 + wv;     // wave id in [0, 14336)
    const int q   = W / 14;
    const int i   = W - q * 14;       // this wave's output row
    const int b   = q >> 9;

    const int4 rr = ((const int4*)roi)[q];
    const int y1 = rr.x, x1 = rr.y, y2 = rr.z, x2 = rr.w;
    const int sR = x2 - x1;           // H-extent from x coords (reference swap)
    const int sC = y2 - y1;           // W-extent from y coords

    // Row constants for this wave (fixed rows r0, r1)
    const int pr  = i * sR;
    const int ir0 = pr / 14;
    const float fr  = (float)(pr - ir0 * 14) * (1.0f / 14.0f);
    const float wr1 = 1.0f - fr;
    const int r0 = ir0;
    const int r1 = min(ir0 + 1, sR - 1);

    const size_t SB4 = (size_t)128 * 128 * 64;   // f32x4 strides
    const size_t SR4 = (size_t)128 * 64;
    const f32x4* base = (const f32x4*)feat + (size_t)b * SB4
                        + (size_t)x1 * SR4 + (size_t)y1 * 64 + lane;
    const f32x4* rowA = base + (size_t)r0 * SR4;   // row r0, column-indexed
    const f32x4* rowB = base + (size_t)r1 * SR4;

    // Prologue: columns 0 and cB=min(1,sC-1)=1 (sC >= 8)
    int cA = 0, cB = min(1, sC - 1);
    f32x4 a0 = rowA[0];
    f32x4 a1 = rowA[(size_t)cB * 64];
    f32x4 b0 = rowB[0];
    f32x4 b1 = rowB[(size_t)cB * 64];

    f32x4* outp = (f32x4*)out + ((size_t)q * 196 + (size_t)i * 14) * 64 + lane;

    for (int j = 0; j < 14; ++j) {
        const int pc = j * sC;                    // cA == pc/14 (invariant)
        const float fc = (float)(pc - cA * 14) * (1.0f / 14.0f);

        // Prefetch next step's new column (wave-uniform branch).
        int nA = cA, nB = cB;
        f32x4 p0, p1;
        bool adv = false;
        if (j < 13) {
            nA = ((j + 1) * sC) / 14;
            nB = min(nA + 1, sC - 1);
            if (nB > cB) {
                p0 = rowA[(size_t)nB * 64];
                p1 = rowB[(size_t)nB * 64];
                adv = true;
            }
        }

        f32x4 o = (a0 * (1.0f - fc) + a1 * fc) * wr1 + (b0 * (1.0f - fc) + b1 * fc) * fr;

        // Streaming store, contiguous across j (1 KB per step per wave).
        f32x4* p = outp + (size_t)j * 64;
        asm volatile("global_store_dwordx4 %0, %1, off sc0 sc1 nt"
                     :: "v"(p), "v"(o) : "memory");

        if (nA > cA) { a0 = a1; b0 = b1; }        // adv => nA > cA; coherent
        if (adv)     { a1 = p0; b1 = p1; }
        cA = nA; cB = nB;
    }
}

extern "C" void kernel_launch(void* const* d_in, const int* in_sizes, int n_in,
                              void* d_out, int out_size, void* d_ws, size_t ws_size,
                              hipStream_t stream) {
    const float* feat = (const float*)d_in[0];
    const int*   roi  = (const int*)d_in[1];
    float* out = (float*)d_out;

    rpn_pool_kernel<<<NBLK, THREADS, 0, stream>>>(feat, roi, out);
}